// Round 9
// baseline (663.017 us; speedup 1.0000x reference)
//
#include <hip/hip_runtime.h>
#include <hip/hip_bf16.h>
#include <math.h>

__device__ __forceinline__ unsigned f2u(float f) {
    unsigned b = __float_as_uint(f);
    return b ^ ((unsigned)((int)b >> 31) | 0x80000000u);
}
__device__ __forceinline__ float u2f(unsigned u) {
    unsigned b = (u & 0x80000000u) ? (u ^ 0x80000000u) : ~u;
    return __uint_as_float(b);
}

// wave-level exact k=16 radix select over 256 values (4 per lane).
__device__ __forceinline__ void radix16(unsigned u0, unsigned u1, unsigned u2, unsigned u3,
                                        unsigned& T, int& kk) {
    unsigned prefix = 0; int k = 16;
    for (int b = 31; b >= 0; --b) {
        unsigned hi = (prefix >> b) | 1u;
        int cnt = __popcll(__ballot((u0 >> b) == hi))
                + __popcll(__ballot((u1 >> b) == hi))
                + __popcll(__ballot((u2 >> b) == hi))
                + __popcll(__ballot((u3 >> b) == hi));
        if (cnt >= k) prefix |= (1u << b); else k -= cnt;
    }
    T = prefix; kk = k;
}

// ---------------- Kernel 1: q = x @ Wq^T ----------------
__global__ __launch_bounds__(256) void k1_gemm(const float* __restrict__ A,
                                               const float* __restrict__ B,
                                               float* __restrict__ C) {
    __shared__ float As[16][128];
    __shared__ float Bs[16][128];
    int t  = threadIdx.x;
    int tx = t & 15, ty = t >> 4;
    int m0 = blockIdx.y * 128, n0 = blockIdx.x * 128;
    float acc[8][8] = {};
    for (int k0 = 0; k0 < 512; k0 += 16) {
#pragma unroll
        for (int i = 0; i < 2; ++i) {
            int u   = t * 2 + i;
            int row = u >> 2;
            int kc  = (u & 3) << 2;
            float4 av = *(const float4*)&A[(m0 + row) * 512 + k0 + kc];
            float4 bv = *(const float4*)&B[(n0 + row) * 512 + k0 + kc];
            As[kc + 0][row] = av.x; As[kc + 1][row] = av.y; As[kc + 2][row] = av.z; As[kc + 3][row] = av.w;
            Bs[kc + 0][row] = bv.x; Bs[kc + 1][row] = bv.y; Bs[kc + 2][row] = bv.z; Bs[kc + 3][row] = bv.w;
        }
        __syncthreads();
#pragma unroll
        for (int kk = 0; kk < 16; ++kk) {
            float4 a0 = *(const float4*)&As[kk][ty * 8];
            float4 a1 = *(const float4*)&As[kk][ty * 8 + 4];
            float4 b0 = *(const float4*)&Bs[kk][tx * 8];
            float4 b1 = *(const float4*)&Bs[kk][tx * 8 + 4];
            float a[8] = {a0.x, a0.y, a0.z, a0.w, a1.x, a1.y, a1.z, a1.w};
            float b[8] = {b0.x, b0.y, b0.z, b0.w, b1.x, b1.y, b1.z, b1.w};
#pragma unroll
            for (int i = 0; i < 8; ++i)
#pragma unroll
                for (int j = 0; j < 8; ++j) acc[i][j] += a[i] * b[j];
        }
        __syncthreads();
    }
#pragma unroll
    for (int i = 0; i < 8; ++i) {
        int m = m0 + ty * 8 + i;
        float4 o0; o0.x = acc[i][0]; o0.y = acc[i][1]; o0.z = acc[i][2]; o0.w = acc[i][3];
        float4 o1; o1.x = acc[i][4]; o1.y = acc[i][5]; o1.z = acc[i][6]; o1.w = acc[i][7];
        *(float4*)&C[m * 4096 + n0 + tx * 8]     = o0;
        *(float4*)&C[m * 4096 + n0 + tx * 8 + 4] = o1;
    }
}

// ---------------- Kernel 2: sim + radix top16 + combine + radix top16 + softmax ----------------
// grid: 2(c)*8(h)*32(ntile 32) = 512 blocks, 256 threads.
// KROW=12: 16B-aligned ds_read_b128, 4-bank starts tile all 32 banks (<=2-way, free).
// Key prefetch issued at TOP of chunk -> lands before the barrier's vmcnt(0) drain.
// q loads laundered into VGPR pointer -> vector loads on vmcnt (decoupled from lgkmcnt).
#define KROW 12
#define PSTRIDE (256 * KROW)
#define BUFSTRIDE (2 * PSTRIDE)
__global__ __launch_bounds__(256) void k2_scores(const float* __restrict__ q,
                                                 const float* __restrict__ keys,
                                                 int* __restrict__ widx,
                                                 float* __restrict__ wcoef) {
    int bid = blockIdx.x;
    int cc = bid & 1;
    int h  = (bid >> 1) & 7;
    int n0 = (bid >> 4) * 32;

    __shared__ float K_s[2][2][PSTRIDE];   // 48 KB: [buf][p][k*KROW + d]
    __shared__ float sx_s[2][32][16];      // 4 KB
    __shared__ int   ix_s[2][32][16];      // 4 KB

    int t = threadIdx.x;
    int wv = t >> 6, ln = t & 63;
    int wvu = __builtin_amdgcn_readfirstlane(wv);
    int pu  = wvu >> 1;
    int nhu = wvu & 1;
    unsigned long long lt = (1ull << ln) - 1ull;

    // wave-uniform q base, laundered into VGPRs so loads are vector (vmcnt)
    const float* qv = q + ((size_t)(pu * 1024 + n0 + nhu * 16) * 4096 + cc * 2048 + h * 256);
    asm volatile("" : "+v"(qv));

    float acc[16][4];
#pragma unroll
    for (int n = 0; n < 16; ++n)
#pragma unroll
        for (int j = 0; j < 4; ++j) acc[n][j] = 0.f;

    // staging: chunk = 2p x 256k x 8d floats = 1024 float4; 4 per thread
    int v0 = t, v1 = t + 256, v2 = t + 512, v3 = t + 768;
    int pp0 = v0 >> 9, k_0 = (v0 >> 1) & 255, s0 = v0 & 1;
    int pp1 = v1 >> 9, k_1 = (v1 >> 1) & 255, s1 = v1 & 1;
    int pp2 = v2 >> 9, k_2 = (v2 >> 1) & 255, s2 = v2 & 1;
    int pp3 = v3 >> 9, k_3 = (v3 >> 1) & 255, s3 = v3 & 1;
    const float* g0 = &keys[(size_t)(((h * 256 + k_0) * 2) + pp0) * 256 + s0 * 4];
    const float* g1 = &keys[(size_t)(((h * 256 + k_1) * 2) + pp1) * 256 + s1 * 4];
    const float* g2 = &keys[(size_t)(((h * 256 + k_2) * 2) + pp2) * 256 + s2 * 4];
    const float* g3 = &keys[(size_t)(((h * 256 + k_3) * 2) + pp3) * 256 + s3 * 4];
    int o0 = pp0 * PSTRIDE + k_0 * KROW + s0 * 4;
    int o1 = pp1 * PSTRIDE + k_1 * KROW + s1 * 4;
    int o2 = pp2 * PSTRIDE + k_2 * KROW + s2 * 4;
    int o3 = pp3 * PSTRIDE + k_3 * KROW + s3 * 4;
    float* lbase = &K_s[0][0][0];
    const float* kbase = &K_s[0][0][0] + pu * PSTRIDE;

    float4 qP[8], qQ[8];
    float4 stA0, stA1, stA2, stA3, stB0, stB1, stB2, stB3;

    // prologue: chunk 0 -> buf0 directly; stB <- chunk 1; qP <- (0, s0, rows 0-7)
    stA0 = *(const float4*)&g0[0];
    stA1 = *(const float4*)&g1[0];
    stA2 = *(const float4*)&g2[0];
    stA3 = *(const float4*)&g3[0];
    *(float4*)(lbase + o0) = stA0;
    *(float4*)(lbase + o1) = stA1;
    *(float4*)(lbase + o2) = stA2;
    *(float4*)(lbase + o3) = stA3;
    stB0 = *(const float4*)&g0[8];
    stB1 = *(const float4*)&g1[8];
    stB2 = *(const float4*)&g2[8];
    stB3 = *(const float4*)&g3[8];
#pragma unroll
    for (int i = 0; i < 8; ++i) qP[i] = *(const float4*)&qv[(size_t)i * 4096];
    __syncthreads();

#define FMA_HALF(QB, ROW0, K0, K1, K2, K3)                                          \
    {                                                                               \
        _Pragma("unroll")                                                           \
        for (int i = 0; i < 8; ++i) {                                               \
            float4 qx = QB[i];                                                      \
            acc[ROW0 + i][0] += qx.x * K0.x + qx.y * K0.y + qx.z * K0.z + qx.w * K0.w; \
            acc[ROW0 + i][1] += qx.x * K1.x + qx.y * K1.y + qx.z * K1.z + qx.w * K1.w; \
            acc[ROW0 + i][2] += qx.x * K2.x + qx.y * K2.y + qx.z * K2.z + qx.w * K2.w; \
            acc[ROW0 + i][3] += qx.x * K3.x + qx.y * K3.y + qx.z * K3.z + qx.w * K3.w; \
        }                                                                           \
    }

#define COMPUTE_CHUNK(CH)                                                            \
    {                                                                                \
        const float* rb = kbase + ((CH) & 1) * BUFSTRIDE;                            \
        /* s = 0 */                                                                  \
        {                                                                            \
            float4 k0 = *(const float4*)&rb[(ln      ) * KROW];                      \
            float4 k1 = *(const float4*)&rb[(ln +  64) * KROW];                      \
            float4 k2 = *(const float4*)&rb[(ln + 128) * KROW];                      \
            float4 k3 = *(const float4*)&rb[(ln + 192) * KROW];                      \
            _Pragma("unroll")                                                        \
            for (int i = 0; i < 8; ++i)                                              \
                qQ[i] = *(const float4*)&qv[(size_t)(8 + i) * 4096 + (CH) * 8];      \
            FMA_HALF(qP, 0, k0, k1, k2, k3);                                         \
            _Pragma("unroll")                                                        \
            for (int i = 0; i < 8; ++i)                                              \
                qP[i] = *(const float4*)&qv[(size_t)i * 4096 + (CH) * 8 + 4];        \
            FMA_HALF(qQ, 8, k0, k1, k2, k3);                                         \
        }                                                                            \
        /* s = 1 */                                                                  \
        {                                                                            \
            float4 k0 = *(const float4*)&rb[(ln      ) * KROW + 4];                  \
            float4 k1 = *(const float4*)&rb[(ln +  64) * KROW + 4];                  \
            float4 k2 = *(const float4*)&rb[(ln + 128) * KROW + 4];                  \
            float4 k3 = *(const float4*)&rb[(ln + 192) * KROW + 4];                  \
            _Pragma("unroll")                                                        \
            for (int i = 0; i < 8; ++i)                                              \
                qQ[i] = *(const float4*)&qv[(size_t)(8 + i) * 4096 + (CH) * 8 + 4];  \
            FMA_HALF(qP, 0, k0, k1, k2, k3);                                         \
            if ((CH) + 1 < 32) {                                                     \
                _Pragma("unroll")                                                    \
                for (int i = 0; i < 8; ++i)                                          \
                    qP[i] = *(const float4*)&qv[(size_t)i * 4096 + ((CH) + 1) * 8];  \
            }                                                                        \
            FMA_HALF(qQ, 8, k0, k1, k2, k3);                                         \
        }                                                                            \
    }

    for (int ch = 0; ch < 32; ch += 2) {
        // ---------- even chunk ch (reads buf0) ----------
        {
            // issue key prefetch for chunk ch+2 EARLY (lands before the barrier drain)
            if (ch + 2 < 32) {
                stA0 = *(const float4*)&g0[(ch + 2) * 8];
                stA1 = *(const float4*)&g1[(ch + 2) * 8];
                stA2 = *(const float4*)&g2[(ch + 2) * 8];
                stA3 = *(const float4*)&g3[(ch + 2) * 8];
            }
            COMPUTE_CHUNK(ch);
            // write chunk ch+1 (stB, loaded 2 chunks ago) -> buf1
            float* wb = lbase + BUFSTRIDE;
            *(float4*)(wb + o0) = stB0;
            *(float4*)(wb + o1) = stB1;
            *(float4*)(wb + o2) = stB2;
            *(float4*)(wb + o3) = stB3;
            __syncthreads();
        }
        // ---------- odd chunk ch+1 (reads buf1) ----------
        {
            if (ch + 3 < 32) {
                stB0 = *(const float4*)&g0[(ch + 3) * 8];
                stB1 = *(const float4*)&g1[(ch + 3) * 8];
                stB2 = *(const float4*)&g2[(ch + 3) * 8];
                stB3 = *(const float4*)&g3[(ch + 3) * 8];
            }
            COMPUTE_CHUNK(ch + 1);
            if (ch + 2 < 32) {
                // write chunk ch+2 (stA) -> buf0
                *(float4*)(lbase + o0) = stA0;
                *(float4*)(lbase + o1) = stA1;
                *(float4*)(lbase + o2) = stA2;
                *(float4*)(lbase + o3) = stA3;
                __syncthreads();
            }
        }
    }
#undef COMPUTE_CHUNK
#undef FMA_HALF
    __syncthreads();   // drain all K-loop LDS traffic before topk phase

    // ---- top-16 per (pu, row): radix select + ballot compaction; key id = ln + 64*slot ----
#pragma unroll
    for (int n = 0; n < 16; ++n) {
        int nn = nhu * 16 + n;
        unsigned u0 = f2u(acc[n][0]), u1 = f2u(acc[n][1]);
        unsigned u2 = f2u(acc[n][2]), u3 = f2u(acc[n][3]);
        unsigned T; int kk;
        radix16(u0, u1, u2, u3, T, kk);
        int base = 0;
#define TK1_GT(J, UJ, VJ) { unsigned long long m = __ballot(UJ > T);            \
        if (UJ > T) { int pos = base + __popcll(m & lt);                        \
            sx_s[pu][nn][pos] = VJ; ix_s[pu][nn][pos] = ln + 64 * J; }          \
        base += __popcll(m); }
        TK1_GT(0, u0, acc[n][0]); TK1_GT(1, u1, acc[n][1]);
        TK1_GT(2, u2, acc[n][2]); TK1_GT(3, u3, acc[n][3]);
#undef TK1_GT
#define TK1_EQ(J, UJ, VJ) { unsigned long long m = __ballot(UJ == T);           \
        int r = __popcll(m & lt);                                               \
        if ((UJ == T) && r < kk) { sx_s[pu][nn][base + r] = VJ;                 \
            ix_s[pu][nn][base + r] = ln + 64 * J; }                             \
        int cn = __popcll(m); int tk = cn < kk ? cn : kk;                       \
        base += tk; kk -= tk; }
        TK1_EQ(0, u0, acc[n][0]); TK1_EQ(1, u1, acc[n][1]);
        TK1_EQ(2, u2, acc[n][2]); TK1_EQ(3, u3, acc[n][3]);
#undef TK1_EQ
    }
    __syncthreads();

    // ---- combine 16x16, radix top-16, softmax: 8 tasks per wave ----
    for (int task = wv * 8; task < wv * 8 + 8; ++task) {
        int n = task;
        int t0 = ln, t1 = ln + 64, t2 = ln + 128, t3 = ln + 192;
        float vc0 = sx_s[0][n][t0 >> 4] + sx_s[1][n][t0 & 15];
        float vc1 = sx_s[0][n][t1 >> 4] + sx_s[1][n][t1 & 15];
        float vc2 = sx_s[0][n][t2 >> 4] + sx_s[1][n][t2 & 15];
        float vc3 = sx_s[0][n][t3 >> 4] + sx_s[1][n][t3 & 15];
        unsigned u0 = f2u(vc0), u1 = f2u(vc1), u2 = f2u(vc2), u3 = f2u(vc3);
        unsigned T; int kk;
        radix16(u0, u1, u2, u3, T, kk);
        float Tf = u2f(T);

        bool w0 = u0 > T, w1 = u1 > T, w2 = u2 > T, w3 = u3 > T;
        int q0 = 0, q1 = 0, q2 = 0, q3 = 0;
        int base = 0;
        { unsigned long long m = __ballot(w0); q0 = base + __popcll(m & lt); base += __popcll(m); }
        { unsigned long long m = __ballot(w1); q1 = base + __popcll(m & lt); base += __popcll(m); }
        { unsigned long long m = __ballot(w2); q2 = base + __popcll(m & lt); base += __popcll(m); }
        { unsigned long long m = __ballot(w3); q3 = base + __popcll(m & lt); base += __popcll(m); }
#define CMB_EQ(UJ, WJ, QJ) { unsigned long long m = __ballot(UJ == T);          \
        int r = __popcll(m & lt);                                               \
        if ((UJ == T) && r < kk) { WJ = true; QJ = base + r; }                  \
        int cn = __popcll(m); int tk = cn < kk ? cn : kk;                       \
        base += tk; kk -= tk; }
        CMB_EQ(u0, w0, q0); CMB_EQ(u1, w1, q1); CMB_EQ(u2, w2, q2); CMB_EQ(u3, w3, q3);
#undef CMB_EQ

        float e0 = 0.f, e1 = 0.f, e2 = 0.f, e3 = 0.f;
        int id0 = 0, id1 = 0, id2 = 0, id3 = 0;
        float es = 0.f;
        if (w0) { e0 = __expf(vc0 - Tf); es += e0; id0 = ix_s[0][n][t0 >> 4] * 256 + ix_s[1][n][t0 & 15]; }
        if (w1) { e1 = __expf(vc1 - Tf); es += e1; id1 = ix_s[0][n][t1 >> 4] * 256 + ix_s[1][n][t1 & 15]; }
        if (w2) { e2 = __expf(vc2 - Tf); es += e2; id2 = ix_s[0][n][t2 >> 4] * 256 + ix_s[1][n][t2 & 15]; }
        if (w3) { e3 = __expf(vc3 - Tf); es += e3; id3 = ix_s[0][n][t3 >> 4] * 256 + ix_s[1][n][t3 & 15]; }
        for (int s = 1; s < 64; s <<= 1) es += __shfl_xor(es, s);
        float inv = 1.f / es;

        int off = ((cc * 1024 + n0 + n) * 8 + h) * 16;
        if (w0) { wcoef[off + q0] = e0 * inv; widx[off + q0] = id0; }
        if (w1) { wcoef[off + q1] = e1 * inv; widx[off + q1] = id1; }
        if (w2) { wcoef[off + q2] = e2 * inv; widx[off + q2] = id2; }
        if (w3) { wcoef[off + q3] = e3 * inv; widx[off + q3] = id3; }
    }
}

// ---------------- Kernel 3: gather experts, gelu, weighted mix ----------------
__global__ __launch_bounds__(256) void k3_experts(const float* __restrict__ x,
                                                  const float* __restrict__ w_down,
                                                  const float* __restrict__ w_up,
                                                  const int* __restrict__ widx,
                                                  const float* __restrict__ wcoef,
                                                  float* __restrict__ out) {
    int bid = blockIdx.x;
    int c = bid >> 10, n = bid & 1023;
    int t = threadIdx.x, wv = t >> 6, ln = t & 63;
    __shared__ float wacc[4][512];

    const float* xrow = &x[(c * 1024 + n) * 512];
    float xr[8], oacc[8];
    {
        float4 xa = *(const float4*)&xrow[ln * 8];
        float4 xb = *(const float4*)&xrow[ln * 8 + 4];
        xr[0] = xa.x; xr[1] = xa.y; xr[2] = xa.z; xr[3] = xa.w;
        xr[4] = xb.x; xr[5] = xb.y; xr[6] = xb.z; xr[7] = xb.w;
    }
#pragma unroll
    for (int j = 0; j < 8; ++j) oacc[j] = 0.f;

    const int base = (c * 1024 + n) * 128;
    for (int e = wv * 32; e < wv * 32 + 32; ++e) {
        int   idx = widx[base + e];
        float wgt = wcoef[base + e];
        const float* dr = &w_down[(long)idx * 512 + ln * 8];
        float4 da = *(const float4*)&dr[0];
        float4 db = *(const float4*)&dr[4];
        float part = da.x * xr[0] + da.y * xr[1] + da.z * xr[2] + da.w * xr[3]
                   + db.x * xr[4] + db.y * xr[5] + db.z * xr[6] + db.w * xr[7];
        for (int s = 1; s < 64; s <<= 1) part += __shfl_xor(part, s);
        float hv = part;
        float coef = 0.5f * hv * (1.f + erff(hv * 0.70710678118654752f)) * wgt;
        const float* ur = &w_up[(long)idx * 512 + ln * 8];
        float4 ua = *(const float4*)&ur[0];
        float4 ub = *(const float4*)&ur[4];
        oacc[0] += coef * ua.x; oacc[1] += coef * ua.y; oacc[2] += coef * ua.z; oacc[3] += coef * ua.w;
        oacc[4] += coef * ub.x; oacc[5] += coef * ub.y; oacc[6] += coef * ub.z; oacc[7] += coef * ub.w;
    }
#pragma unroll
    for (int j = 0; j < 8; ++j) wacc[wv][ln * 8 + j] = oacc[j];
    __syncthreads();

    float* orow = &out[(c * 1024 + n) * 512];
    for (int d = t; d < 512; d += 256)
        orow[d] = wacc[0][d] + wacc[1][d] + wacc[2][d] + wacc[3][d];
}

extern "C" void kernel_launch(void* const* d_in, const int* in_sizes, int n_in,
                              void* d_out, int out_size, void* d_ws, size_t ws_size,
                              hipStream_t stream) {
    const float* x      = (const float*)d_in[0];
    const float* Wq     = (const float*)d_in[1];
    const float* keys   = (const float*)d_in[2];
    const float* w_down = (const float*)d_in[3];
    const float* w_up   = (const float*)d_in[4];
    float* out = (float*)d_out;

    char* ws = (char*)d_ws;
    float* q     = (float*)ws;                               // 32 MiB
    int*   widx  = (int*)(ws + 2048UL * 4096 * 4);           // 1 MiB
    float* wcoef = (float*)(ws + 2048UL * 4096 * 4 + 262144UL * 4);

    k1_gemm<<<dim3(32, 16), 256, 0, stream>>>(x, Wq, q);
    k2_scores<<<512, 256, 0, stream>>>(q, keys, widx, wcoef);
    k3_experts<<<2048, 256, 0, stream>>>(x, w_down, w_up, widx, wcoef, out);
}

// Round 10
// 390.104 us; speedup vs baseline: 1.6996x; 1.6996x over previous
//
#include <hip/hip_runtime.h>
#include <hip/hip_bf16.h>
#include <math.h>

__device__ __forceinline__ unsigned f2u(float f) {
    unsigned b = __float_as_uint(f);
    return b ^ ((unsigned)((int)b >> 31) | 0x80000000u);
}
__device__ __forceinline__ float u2f(unsigned u) {
    unsigned b = (u & 0x80000000u) ? (u ^ 0x80000000u) : ~u;
    return __uint_as_float(b);
}

// wave-level exact k=16 radix select over 256 values (4 per lane).
__device__ __forceinline__ void radix16(unsigned u0, unsigned u1, unsigned u2, unsigned u3,
                                        unsigned& T, int& kk) {
    unsigned prefix = 0; int k = 16;
    for (int b = 31; b >= 0; --b) {
        unsigned hi = (prefix >> b) | 1u;
        int cnt = __popcll(__ballot((u0 >> b) == hi))
                + __popcll(__ballot((u1 >> b) == hi))
                + __popcll(__ballot((u2 >> b) == hi))
                + __popcll(__ballot((u3 >> b) == hi));
        if (cnt >= k) prefix |= (1u << b); else k -= cnt;
    }
    T = prefix; kk = k;
}

// ---------------- Kernel 0: key transpose ----------------
// keys[((h*256+k)*2+p)*256+d] -> KT[((h*2+p)*256+d)*256+k]
__global__ __launch_bounds__(256) void k0_transpose(const float* __restrict__ keys,
                                                    float* __restrict__ KT) {
    int bid = blockIdx.x;               // 8h * 2p * 4kt * 4dt = 256 blocks
    int dt = bid & 3, ktile = (bid >> 2) & 3, p = (bid >> 4) & 1, h = bid >> 5;
    __shared__ float tile[64][65];
    int t = threadIdx.x;
    int row = t >> 2;      // 0..63
    int c4  = t & 3;       // 0..3
#pragma unroll
    for (int i = 0; i < 4; ++i) {
        int dloc = (c4 + 4 * i) * 4;   // 0..60
        float4 v = *(const float4*)&keys[(size_t)(((h * 256 + ktile * 64 + row) * 2 + p) * 256) + dt * 64 + dloc];
        tile[dloc + 0][row] = v.x;
        tile[dloc + 1][row] = v.y;
        tile[dloc + 2][row] = v.z;
        tile[dloc + 3][row] = v.w;
    }
    __syncthreads();
#pragma unroll
    for (int i = 0; i < 4; ++i) {
        int kloc = (c4 + 4 * i) * 4;
        float4 v;
        v.x = tile[row][kloc]; v.y = tile[row][kloc + 1];
        v.z = tile[row][kloc + 2]; v.w = tile[row][kloc + 3];
        *(float4*)&KT[(size_t)((h * 2 + p) * 256 + dt * 64 + row) * 256 + ktile * 64 + kloc] = v;
    }
}

// ---------------- Kernel 1: q = x @ Wq^T ----------------
__global__ __launch_bounds__(256) void k1_gemm(const float* __restrict__ A,
                                               const float* __restrict__ B,
                                               float* __restrict__ C) {
    __shared__ float As[16][128];
    __shared__ float Bs[16][128];
    int t  = threadIdx.x;
    int tx = t & 15, ty = t >> 4;
    int m0 = blockIdx.y * 128, n0 = blockIdx.x * 128;
    float acc[8][8] = {};
    for (int k0 = 0; k0 < 512; k0 += 16) {
#pragma unroll
        for (int i = 0; i < 2; ++i) {
            int u   = t * 2 + i;
            int row = u >> 2;
            int kc  = (u & 3) << 2;
            float4 av = *(const float4*)&A[(m0 + row) * 512 + k0 + kc];
            float4 bv = *(const float4*)&B[(n0 + row) * 512 + k0 + kc];
            As[kc + 0][row] = av.x; As[kc + 1][row] = av.y; As[kc + 2][row] = av.z; As[kc + 3][row] = av.w;
            Bs[kc + 0][row] = bv.x; Bs[kc + 1][row] = bv.y; Bs[kc + 2][row] = bv.z; Bs[kc + 3][row] = bv.w;
        }
        __syncthreads();
#pragma unroll
        for (int kk = 0; kk < 16; ++kk) {
            float4 a0 = *(const float4*)&As[kk][ty * 8];
            float4 a1 = *(const float4*)&As[kk][ty * 8 + 4];
            float4 b0 = *(const float4*)&Bs[kk][tx * 8];
            float4 b1 = *(const float4*)&Bs[kk][tx * 8 + 4];
            float a[8] = {a0.x, a0.y, a0.z, a0.w, a1.x, a1.y, a1.z, a1.w};
            float b[8] = {b0.x, b0.y, b0.z, b0.w, b1.x, b1.y, b1.z, b1.w};
#pragma unroll
            for (int i = 0; i < 8; ++i)
#pragma unroll
                for (int j = 0; j < 8; ++j) acc[i][j] += a[i] * b[j];
        }
        __syncthreads();
    }
#pragma unroll
    for (int i = 0; i < 8; ++i) {
        int m = m0 + ty * 8 + i;
        float4 o0; o0.x = acc[i][0]; o0.y = acc[i][1]; o0.z = acc[i][2]; o0.w = acc[i][3];
        float4 o1; o1.x = acc[i][4]; o1.y = acc[i][5]; o1.z = acc[i][6]; o1.w = acc[i][7];
        *(float4*)&C[m * 4096 + n0 + tx * 8]     = o0;
        *(float4*)&C[m * 4096 + n0 + tx * 8 + 4] = o1;
    }
}

// ---------------- Kernel 2: sim + radix top16 + combine + radix top16 + softmax ----------------
// grid: 2(c)*8(h)*64(ntile 16) = 1024 blocks, 256 threads -> 4 blocks/CU.
// Wave wv -> (pu = wv>>1, nhu = wv&1), 8 q-rows each; acc[8][4] in registers.
// NO LDS, NO barriers in the score loop: keys read coalesced from KT[h][p][d][k]
// (lane ln owns keys 4ln..4ln+3; 8 independent dwordx4 loads in flight per step),
// q read via wave-uniform (scalar) loads.
__global__ __launch_bounds__(256) void k2_scores(const float* __restrict__ q,
                                                 const float* __restrict__ KT,
                                                 int* __restrict__ widx,
                                                 float* __restrict__ wcoef) {
    int bid = blockIdx.x;
    int cc = bid & 1;
    int h  = (bid >> 1) & 7;
    int n0 = (bid >> 4) * 16;

    __shared__ float sx_s[2][16][16];      // 2 KB
    __shared__ int   ix_s[2][16][16];      // 2 KB

    int t = threadIdx.x;
    int wv = t >> 6, ln = t & 63;
    int wvu = __builtin_amdgcn_readfirstlane(wv);
    int pu  = wvu >> 1;
    int nhu = wvu & 1;
    unsigned long long lt = (1ull << ln) - 1ull;

    // wave-uniform q base: 8 rows starting at pu*1024 + n0 + nhu*8
    const float* qw = q + ((size_t)(pu * 1024 + n0 + nhu * 8) * 4096 + cc * 2048 + h * 256);
    // per-lane key base: KT[h][pu][*][4*ln]
    const float* kp = KT + (size_t)((h * 2 + pu) * 256) * 256 + 4 * ln;

    float acc[8][4];
#pragma unroll
    for (int n = 0; n < 8; ++n)
#pragma unroll
        for (int j = 0; j < 4; ++j) acc[n][j] = 0.f;

    for (int d0 = 0; d0 < 256; d0 += 8) {
        float4 kt[8];
#pragma unroll
        for (int dd = 0; dd < 8; ++dd)
            kt[dd] = *(const float4*)&kp[(size_t)(d0 + dd) * 256];
#pragma unroll
        for (int n = 0; n < 8; ++n) {
            float4 qa = *(const float4*)&qw[(size_t)n * 4096 + d0];
            float4 qb = *(const float4*)&qw[(size_t)n * 4096 + d0 + 4];
            acc[n][0] += qa.x * kt[0].x + qa.y * kt[1].x + qa.z * kt[2].x + qa.w * kt[3].x
                       + qb.x * kt[4].x + qb.y * kt[5].x + qb.z * kt[6].x + qb.w * kt[7].x;
            acc[n][1] += qa.x * kt[0].y + qa.y * kt[1].y + qa.z * kt[2].y + qa.w * kt[3].y
                       + qb.x * kt[4].y + qb.y * kt[5].y + qb.z * kt[6].y + qb.w * kt[7].y;
            acc[n][2] += qa.x * kt[0].z + qa.y * kt[1].z + qa.z * kt[2].z + qa.w * kt[3].z
                       + qb.x * kt[4].z + qb.y * kt[5].z + qb.z * kt[6].z + qb.w * kt[7].z;
            acc[n][3] += qa.x * kt[0].w + qa.y * kt[1].w + qa.z * kt[2].w + qa.w * kt[3].w
                       + qb.x * kt[4].w + qb.y * kt[5].w + qb.z * kt[6].w + qb.w * kt[7].w;
        }
    }

    // ---- top-16 per (pu, row): radix select + ballot compaction; key id = 4*ln + J ----
#pragma unroll
    for (int n = 0; n < 8; ++n) {
        int nn = nhu * 8 + n;
        unsigned u0 = f2u(acc[n][0]), u1 = f2u(acc[n][1]);
        unsigned u2 = f2u(acc[n][2]), u3 = f2u(acc[n][3]);
        unsigned T; int kk;
        radix16(u0, u1, u2, u3, T, kk);
        int base = 0;
#define TK1_GT(J, UJ, VJ) { unsigned long long m = __ballot(UJ > T);            \
        if (UJ > T) { int pos = base + __popcll(m & lt);                        \
            sx_s[pu][nn][pos] = VJ; ix_s[pu][nn][pos] = ln * 4 + J; }           \
        base += __popcll(m); }
        TK1_GT(0, u0, acc[n][0]); TK1_GT(1, u1, acc[n][1]);
        TK1_GT(2, u2, acc[n][2]); TK1_GT(3, u3, acc[n][3]);
#undef TK1_GT
#define TK1_EQ(J, UJ, VJ) { unsigned long long m = __ballot(UJ == T);           \
        int r = __popcll(m & lt);                                               \
        if ((UJ == T) && r < kk) { sx_s[pu][nn][base + r] = VJ;                 \
            ix_s[pu][nn][base + r] = ln * 4 + J; }                              \
        int cn = __popcll(m); int tk = cn < kk ? cn : kk;                       \
        base += tk; kk -= tk; }
        TK1_EQ(0, u0, acc[n][0]); TK1_EQ(1, u1, acc[n][1]);
        TK1_EQ(2, u2, acc[n][2]); TK1_EQ(3, u3, acc[n][3]);
#undef TK1_EQ
    }
    __syncthreads();

    // ---- combine 16x16, radix top-16, softmax: 4 tasks per wave ----
    for (int task = wv * 4; task < wv * 4 + 4; ++task) {
        int n = task;
        int t0 = ln, t1 = ln + 64, t2 = ln + 128, t3 = ln + 192;
        float vc0 = sx_s[0][n][t0 >> 4] + sx_s[1][n][t0 & 15];
        float vc1 = sx_s[0][n][t1 >> 4] + sx_s[1][n][t1 & 15];
        float vc2 = sx_s[0][n][t2 >> 4] + sx_s[1][n][t2 & 15];
        float vc3 = sx_s[0][n][t3 >> 4] + sx_s[1][n][t3 & 15];
        unsigned u0 = f2u(vc0), u1 = f2u(vc1), u2 = f2u(vc2), u3 = f2u(vc3);
        unsigned T; int kk;
        radix16(u0, u1, u2, u3, T, kk);
        float Tf = u2f(T);

        bool w0 = u0 > T, w1 = u1 > T, w2 = u2 > T, w3 = u3 > T;
        int q0 = 0, q1 = 0, q2 = 0, q3 = 0;
        int base = 0;
        { unsigned long long m = __ballot(w0); q0 = base + __popcll(m & lt); base += __popcll(m); }
        { unsigned long long m = __ballot(w1); q1 = base + __popcll(m & lt); base += __popcll(m); }
        { unsigned long long m = __ballot(w2); q2 = base + __popcll(m & lt); base += __popcll(m); }
        { unsigned long long m = __ballot(w3); q3 = base + __popcll(m & lt); base += __popcll(m); }
#define CMB_EQ(UJ, WJ, QJ) { unsigned long long m = __ballot(UJ == T);          \
        int r = __popcll(m & lt);                                               \
        if ((UJ == T) && r < kk) { WJ = true; QJ = base + r; }                  \
        int cn = __popcll(m); int tk = cn < kk ? cn : kk;                       \
        base += tk; kk -= tk; }
        CMB_EQ(u0, w0, q0); CMB_EQ(u1, w1, q1); CMB_EQ(u2, w2, q2); CMB_EQ(u3, w3, q3);
#undef CMB_EQ

        float e0 = 0.f, e1 = 0.f, e2 = 0.f, e3 = 0.f;
        int id0 = 0, id1 = 0, id2 = 0, id3 = 0;
        float es = 0.f;
        if (w0) { e0 = __expf(vc0 - Tf); es += e0; id0 = ix_s[0][n][t0 >> 4] * 256 + ix_s[1][n][t0 & 15]; }
        if (w1) { e1 = __expf(vc1 - Tf); es += e1; id1 = ix_s[0][n][t1 >> 4] * 256 + ix_s[1][n][t1 & 15]; }
        if (w2) { e2 = __expf(vc2 - Tf); es += e2; id2 = ix_s[0][n][t2 >> 4] * 256 + ix_s[1][n][t2 & 15]; }
        if (w3) { e3 = __expf(vc3 - Tf); es += e3; id3 = ix_s[0][n][t3 >> 4] * 256 + ix_s[1][n][t3 & 15]; }
        for (int s = 1; s < 64; s <<= 1) es += __shfl_xor(es, s);
        float inv = 1.f / es;

        int off = ((cc * 1024 + n0 + n) * 8 + h) * 16;
        if (w0) { wcoef[off + q0] = e0 * inv; widx[off + q0] = id0; }
        if (w1) { wcoef[off + q1] = e1 * inv; widx[off + q1] = id1; }
        if (w2) { wcoef[off + q2] = e2 * inv; widx[off + q2] = id2; }
        if (w3) { wcoef[off + q3] = e3 * inv; widx[off + q3] = id3; }
    }
}

// ---------------- Kernel 3: gather experts, gelu, weighted mix ----------------
__global__ __launch_bounds__(256) void k3_experts(const float* __restrict__ x,
                                                  const float* __restrict__ w_down,
                                                  const float* __restrict__ w_up,
                                                  const int* __restrict__ widx,
                                                  const float* __restrict__ wcoef,
                                                  float* __restrict__ out) {
    int bid = blockIdx.x;
    int c = bid >> 10, n = bid & 1023;
    int t = threadIdx.x, wv = t >> 6, ln = t & 63;
    __shared__ float wacc[4][512];

    const float* xrow = &x[(c * 1024 + n) * 512];
    float xr[8], oacc[8];
    {
        float4 xa = *(const float4*)&xrow[ln * 8];
        float4 xb = *(const float4*)&xrow[ln * 8 + 4];
        xr[0] = xa.x; xr[1] = xa.y; xr[2] = xa.z; xr[3] = xa.w;
        xr[4] = xb.x; xr[5] = xb.y; xr[6] = xb.z; xr[7] = xb.w;
    }
#pragma unroll
    for (int j = 0; j < 8; ++j) oacc[j] = 0.f;

    const int base = (c * 1024 + n) * 128;
    for (int e = wv * 32; e < wv * 32 + 32; ++e) {
        int   idx = widx[base + e];
        float wgt = wcoef[base + e];
        const float* dr = &w_down[(long)idx * 512 + ln * 8];
        float4 da = *(const float4*)&dr[0];
        float4 db = *(const float4*)&dr[4];
        float part = da.x * xr[0] + da.y * xr[1] + da.z * xr[2] + da.w * xr[3]
                   + db.x * xr[4] + db.y * xr[5] + db.z * xr[6] + db.w * xr[7];
        for (int s = 1; s < 64; s <<= 1) part += __shfl_xor(part, s);
        float hv = part;
        float coef = 0.5f * hv * (1.f + erff(hv * 0.70710678118654752f)) * wgt;
        const float* ur = &w_up[(long)idx * 512 + ln * 8];
        float4 ua = *(const float4*)&ur[0];
        float4 ub = *(const float4*)&ur[4];
        oacc[0] += coef * ua.x; oacc[1] += coef * ua.y; oacc[2] += coef * ua.z; oacc[3] += coef * ua.w;
        oacc[4] += coef * ub.x; oacc[5] += coef * ub.y; oacc[6] += coef * ub.z; oacc[7] += coef * ub.w;
    }
#pragma unroll
    for (int j = 0; j < 8; ++j) wacc[wv][ln * 8 + j] = oacc[j];
    __syncthreads();

    float* orow = &out[(c * 1024 + n) * 512];
    for (int d = t; d < 512; d += 256)
        orow[d] = wacc[0][d] + wacc[1][d] + wacc[2][d] + wacc[3][d];
}

extern "C" void kernel_launch(void* const* d_in, const int* in_sizes, int n_in,
                              void* d_out, int out_size, void* d_ws, size_t ws_size,
                              hipStream_t stream) {
    const float* x      = (const float*)d_in[0];
    const float* Wq     = (const float*)d_in[1];
    const float* keys   = (const float*)d_in[2];
    const float* w_down = (const float*)d_in[3];
    const float* w_up   = (const float*)d_in[4];
    float* out = (float*)d_out;

    char* ws = (char*)d_ws;
    float* q     = (float*)ws;                               // 32 MiB
    int*   widx  = (int*)(ws + 2048UL * 4096 * 4);           // 1 MiB
    float* wcoef = (float*)(ws + 2048UL * 4096 * 4 + 262144UL * 4);
    float* KT    = (float*)(ws + 2048UL * 4096 * 4 + 2 * 262144UL * 4);  // 4 MiB

    k0_transpose<<<256, 256, 0, stream>>>(keys, KT);
    k1_gemm<<<dim3(32, 16), 256, 0, stream>>>(x, Wq, q);
    k2_scores<<<1024, 256, 0, stream>>>(q, KT, widx, wcoef);
    k3_experts<<<2048, 256, 0, stream>>>(x, w_down, w_up, widx, wcoef, out);
}

// Round 11
// 390.050 us; speedup vs baseline: 1.6998x; 1.0001x over previous
//
#include <hip/hip_runtime.h>
#include <hip/hip_bf16.h>
#include <math.h>

__device__ __forceinline__ unsigned f2u(float f) {
    unsigned b = __float_as_uint(f);
    return b ^ ((unsigned)((int)b >> 31) | 0x80000000u);
}
__device__ __forceinline__ float u2f(unsigned u) {
    unsigned b = (u & 0x80000000u) ? (u ^ 0x80000000u) : ~u;
    return __uint_as_float(b);
}

// wave-level exact k=16 radix select over 256 values (4 per lane).
__device__ __forceinline__ void radix16(unsigned u0, unsigned u1, unsigned u2, unsigned u3,
                                        unsigned& T, int& kk) {
    unsigned prefix = 0; int k = 16;
    for (int b = 31; b >= 0; --b) {
        unsigned hi = (prefix >> b) | 1u;
        int cnt = __popcll(__ballot((u0 >> b) == hi))
                + __popcll(__ballot((u1 >> b) == hi))
                + __popcll(__ballot((u2 >> b) == hi))
                + __popcll(__ballot((u3 >> b) == hi));
        if (cnt >= k) prefix |= (1u << b); else k -= cnt;
    }
    T = prefix; kk = k;
}

// ---------------- Kernel 0: key transpose ----------------
// keys[((h*256+k)*2+p)*256+d] -> KT[((h*2+p)*256+d)*256+k]
__global__ __launch_bounds__(256) void k0_transpose(const float* __restrict__ keys,
                                                    float* __restrict__ KT) {
    int bid = blockIdx.x;               // 8h * 2p * 4kt * 4dt = 256 blocks
    int dt = bid & 3, ktile = (bid >> 2) & 3, p = (bid >> 4) & 1, h = bid >> 5;
    __shared__ float tile[64][65];
    int t = threadIdx.x;
    int row = t >> 2;      // 0..63
    int c4  = t & 3;       // 0..3
#pragma unroll
    for (int i = 0; i < 4; ++i) {
        int dloc = (c4 + 4 * i) * 4;   // 0..60
        float4 v = *(const float4*)&keys[(size_t)(((h * 256 + ktile * 64 + row) * 2 + p) * 256) + dt * 64 + dloc];
        tile[dloc + 0][row] = v.x;
        tile[dloc + 1][row] = v.y;
        tile[dloc + 2][row] = v.z;
        tile[dloc + 3][row] = v.w;
    }
    __syncthreads();
#pragma unroll
    for (int i = 0; i < 4; ++i) {
        int kloc = (c4 + 4 * i) * 4;
        float4 v;
        v.x = tile[row][kloc]; v.y = tile[row][kloc + 1];
        v.z = tile[row][kloc + 2]; v.w = tile[row][kloc + 3];
        *(float4*)&KT[(size_t)((h * 2 + p) * 256 + dt * 64 + row) * 256 + ktile * 64 + kloc] = v;
    }
}

// ---------------- Kernel 1: q = x @ Wq^T ----------------
__global__ __launch_bounds__(256) void k1_gemm(const float* __restrict__ A,
                                               const float* __restrict__ B,
                                               float* __restrict__ C) {
    __shared__ float As[16][128];
    __shared__ float Bs[16][128];
    int t  = threadIdx.x;
    int tx = t & 15, ty = t >> 4;
    int m0 = blockIdx.y * 128, n0 = blockIdx.x * 128;
    float acc[8][8] = {};
    for (int k0 = 0; k0 < 512; k0 += 16) {
#pragma unroll
        for (int i = 0; i < 2; ++i) {
            int u   = t * 2 + i;
            int row = u >> 2;
            int kc  = (u & 3) << 2;
            float4 av = *(const float4*)&A[(m0 + row) * 512 + k0 + kc];
            float4 bv = *(const float4*)&B[(n0 + row) * 512 + k0 + kc];
            As[kc + 0][row] = av.x; As[kc + 1][row] = av.y; As[kc + 2][row] = av.z; As[kc + 3][row] = av.w;
            Bs[kc + 0][row] = bv.x; Bs[kc + 1][row] = bv.y; Bs[kc + 2][row] = bv.z; Bs[kc + 3][row] = bv.w;
        }
        __syncthreads();
#pragma unroll
        for (int kk = 0; kk < 16; ++kk) {
            float4 a0 = *(const float4*)&As[kk][ty * 8];
            float4 a1 = *(const float4*)&As[kk][ty * 8 + 4];
            float4 b0 = *(const float4*)&Bs[kk][tx * 8];
            float4 b1 = *(const float4*)&Bs[kk][tx * 8 + 4];
            float a[8] = {a0.x, a0.y, a0.z, a0.w, a1.x, a1.y, a1.z, a1.w};
            float b[8] = {b0.x, b0.y, b0.z, b0.w, b1.x, b1.y, b1.z, b1.w};
#pragma unroll
            for (int i = 0; i < 8; ++i)
#pragma unroll
                for (int j = 0; j < 8; ++j) acc[i][j] += a[i] * b[j];
        }
        __syncthreads();
    }
#pragma unroll
    for (int i = 0; i < 8; ++i) {
        int m = m0 + ty * 8 + i;
        float4 o0; o0.x = acc[i][0]; o0.y = acc[i][1]; o0.z = acc[i][2]; o0.w = acc[i][3];
        float4 o1; o1.x = acc[i][4]; o1.y = acc[i][5]; o1.z = acc[i][6]; o1.w = acc[i][7];
        *(float4*)&C[m * 4096 + n0 + tx * 8]     = o0;
        *(float4*)&C[m * 4096 + n0 + tx * 8 + 4] = o1;
    }
}

// ---------------- Kernel 2: sim + radix top16 + combine + radix top16 + softmax ----------------
// (structure unchanged from round 10: barrier-free coalesced KT reads)
__global__ __launch_bounds__(256) void k2_scores(const float* __restrict__ q,
                                                 const float* __restrict__ KT,
                                                 int* __restrict__ widx,
                                                 float* __restrict__ wcoef) {
    int bid = blockIdx.x;
    int cc = bid & 1;
    int h  = (bid >> 1) & 7;
    int n0 = (bid >> 4) * 16;

    __shared__ float sx_s[2][16][16];
    __shared__ int   ix_s[2][16][16];

    int t = threadIdx.x;
    int wv = t >> 6, ln = t & 63;
    int wvu = __builtin_amdgcn_readfirstlane(wv);
    int pu  = wvu >> 1;
    int nhu = wvu & 1;
    unsigned long long lt = (1ull << ln) - 1ull;

    const float* qw = q + ((size_t)(pu * 1024 + n0 + nhu * 8) * 4096 + cc * 2048 + h * 256);
    const float* kp = KT + (size_t)((h * 2 + pu) * 256) * 256 + 4 * ln;

    float acc[8][4];
#pragma unroll
    for (int n = 0; n < 8; ++n)
#pragma unroll
        for (int j = 0; j < 4; ++j) acc[n][j] = 0.f;

    for (int d0 = 0; d0 < 256; d0 += 8) {
        float4 kt[8];
#pragma unroll
        for (int dd = 0; dd < 8; ++dd)
            kt[dd] = *(const float4*)&kp[(size_t)(d0 + dd) * 256];
#pragma unroll
        for (int n = 0; n < 8; ++n) {
            float4 qa = *(const float4*)&qw[(size_t)n * 4096 + d0];
            float4 qb = *(const float4*)&qw[(size_t)n * 4096 + d0 + 4];
            acc[n][0] += qa.x * kt[0].x + qa.y * kt[1].x + qa.z * kt[2].x + qa.w * kt[3].x
                       + qb.x * kt[4].x + qb.y * kt[5].x + qb.z * kt[6].x + qb.w * kt[7].x;
            acc[n][1] += qa.x * kt[0].y + qa.y * kt[1].y + qa.z * kt[2].y + qa.w * kt[3].y
                       + qb.x * kt[4].y + qb.y * kt[5].y + qb.z * kt[6].y + qb.w * kt[7].y;
            acc[n][2] += qa.x * kt[0].z + qa.y * kt[1].z + qa.z * kt[2].z + qa.w * kt[3].z
                       + qb.x * kt[4].z + qb.y * kt[5].z + qb.z * kt[6].z + qb.w * kt[7].z;
            acc[n][3] += qa.x * kt[0].w + qa.y * kt[1].w + qa.z * kt[2].w + qa.w * kt[3].w
                       + qb.x * kt[4].w + qb.y * kt[5].w + qb.z * kt[6].w + qb.w * kt[7].w;
        }
    }

#pragma unroll
    for (int n = 0; n < 8; ++n) {
        int nn = nhu * 8 + n;
        unsigned u0 = f2u(acc[n][0]), u1 = f2u(acc[n][1]);
        unsigned u2 = f2u(acc[n][2]), u3 = f2u(acc[n][3]);
        unsigned T; int kk;
        radix16(u0, u1, u2, u3, T, kk);
        int base = 0;
#define TK1_GT(J, UJ, VJ) { unsigned long long m = __ballot(UJ > T);            \
        if (UJ > T) { int pos = base + __popcll(m & lt);                        \
            sx_s[pu][nn][pos] = VJ; ix_s[pu][nn][pos] = ln * 4 + J; }           \
        base += __popcll(m); }
        TK1_GT(0, u0, acc[n][0]); TK1_GT(1, u1, acc[n][1]);
        TK1_GT(2, u2, acc[n][2]); TK1_GT(3, u3, acc[n][3]);
#undef TK1_GT
#define TK1_EQ(J, UJ, VJ) { unsigned long long m = __ballot(UJ == T);           \
        int r = __popcll(m & lt);                                               \
        if ((UJ == T) && r < kk) { sx_s[pu][nn][base + r] = VJ;                 \
            ix_s[pu][nn][base + r] = ln * 4 + J; }                              \
        int cn = __popcll(m); int tk = cn < kk ? cn : kk;                       \
        base += tk; kk -= tk; }
        TK1_EQ(0, u0, acc[n][0]); TK1_EQ(1, u1, acc[n][1]);
        TK1_EQ(2, u2, acc[n][2]); TK1_EQ(3, u3, acc[n][3]);
#undef TK1_EQ
    }
    __syncthreads();

    for (int task = wv * 4; task < wv * 4 + 4; ++task) {
        int n = task;
        int t0 = ln, t1 = ln + 64, t2 = ln + 128, t3 = ln + 192;
        float vc0 = sx_s[0][n][t0 >> 4] + sx_s[1][n][t0 & 15];
        float vc1 = sx_s[0][n][t1 >> 4] + sx_s[1][n][t1 & 15];
        float vc2 = sx_s[0][n][t2 >> 4] + sx_s[1][n][t2 & 15];
        float vc3 = sx_s[0][n][t3 >> 4] + sx_s[1][n][t3 & 15];
        unsigned u0 = f2u(vc0), u1 = f2u(vc1), u2 = f2u(vc2), u3 = f2u(vc3);
        unsigned T; int kk;
        radix16(u0, u1, u2, u3, T, kk);
        float Tf = u2f(T);

        bool w0 = u0 > T, w1 = u1 > T, w2 = u2 > T, w3 = u3 > T;
        int q0 = 0, q1 = 0, q2 = 0, q3 = 0;
        int base = 0;
        { unsigned long long m = __ballot(w0); q0 = base + __popcll(m & lt); base += __popcll(m); }
        { unsigned long long m = __ballot(w1); q1 = base + __popcll(m & lt); base += __popcll(m); }
        { unsigned long long m = __ballot(w2); q2 = base + __popcll(m & lt); base += __popcll(m); }
        { unsigned long long m = __ballot(w3); q3 = base + __popcll(m & lt); base += __popcll(m); }
#define CMB_EQ(UJ, WJ, QJ) { unsigned long long m = __ballot(UJ == T);          \
        int r = __popcll(m & lt);                                               \
        if ((UJ == T) && r < kk) { WJ = true; QJ = base + r; }                  \
        int cn = __popcll(m); int tk = cn < kk ? cn : kk;                       \
        base += tk; kk -= tk; }
        CMB_EQ(u0, w0, q0); CMB_EQ(u1, w1, q1); CMB_EQ(u2, w2, q2); CMB_EQ(u3, w3, q3);
#undef CMB_EQ

        float e0 = 0.f, e1 = 0.f, e2 = 0.f, e3 = 0.f;
        int id0 = 0, id1 = 0, id2 = 0, id3 = 0;
        float es = 0.f;
        if (w0) { e0 = __expf(vc0 - Tf); es += e0; id0 = ix_s[0][n][t0 >> 4] * 256 + ix_s[1][n][t0 & 15]; }
        if (w1) { e1 = __expf(vc1 - Tf); es += e1; id1 = ix_s[0][n][t1 >> 4] * 256 + ix_s[1][n][t1 & 15]; }
        if (w2) { e2 = __expf(vc2 - Tf); es += e2; id2 = ix_s[0][n][t2 >> 4] * 256 + ix_s[1][n][t2 & 15]; }
        if (w3) { e3 = __expf(vc3 - Tf); es += e3; id3 = ix_s[0][n][t3 >> 4] * 256 + ix_s[1][n][t3 & 15]; }
        for (int s = 1; s < 64; s <<= 1) es += __shfl_xor(es, s);
        float inv = 1.f / es;

        int off = ((cc * 1024 + n0 + n) * 8 + h) * 16;
        if (w0) { wcoef[off + q0] = e0 * inv; widx[off + q0] = id0; }
        if (w1) { wcoef[off + q1] = e1 * inv; widx[off + q1] = id1; }
        if (w2) { wcoef[off + q2] = e2 * inv; widx[off + q2] = id2; }
        if (w3) { wcoef[off + q3] = e3 * inv; widx[off + q3] = id3; }
    }
}

// ---------------- Kernel 3: gather experts, gelu, weighted mix ----------------
// one block per (c,n); 4 waves x 32 experts; 2-deep software pipeline:
// expert e+1's w_down AND w_up rows are issued before expert e's
// reduce/gelu/accumulate, so loads always have a compute phase to hide under.
__global__ __launch_bounds__(256) void k3_experts(const float* __restrict__ x,
                                                  const float* __restrict__ w_down,
                                                  const float* __restrict__ w_up,
                                                  const int* __restrict__ widx,
                                                  const float* __restrict__ wcoef,
                                                  float* __restrict__ out) {
    int bid = blockIdx.x;
    int c = bid >> 10, n = bid & 1023;
    int t = threadIdx.x, wv = t >> 6, ln = t & 63;
    __shared__ float wacc[4][512];

    const float* xrow = &x[(c * 1024 + n) * 512];
    float xr[8], oacc[8];
    {
        float4 xa = *(const float4*)&xrow[ln * 8];
        float4 xb = *(const float4*)&xrow[ln * 8 + 4];
        xr[0] = xa.x; xr[1] = xa.y; xr[2] = xa.z; xr[3] = xa.w;
        xr[4] = xb.x; xr[5] = xb.y; xr[6] = xb.z; xr[7] = xb.w;
    }
#pragma unroll
    for (int j = 0; j < 8; ++j) oacc[j] = 0.f;

    const int base = (c * 1024 + n) * 128 + wv * 32;
    // hoist this wave's 32 (idx, wgt) pairs into lanes 0-31
    int   myidx = 0;
    float mywgt = 0.f;
    if (ln < 32) { myidx = widx[base + ln]; mywgt = wcoef[base + ln]; }

#define EXPERT_COMPUTE(D0, D1, U0, U1, WGT)                                      \
    {                                                                            \
        float part = D0.x * xr[0] + D0.y * xr[1] + D0.z * xr[2] + D0.w * xr[3]   \
                   + D1.x * xr[4] + D1.y * xr[5] + D1.z * xr[6] + D1.w * xr[7];  \
        for (int s = 1; s < 64; s <<= 1) part += __shfl_xor(part, s);            \
        float coef = 0.5f * part * (1.f + erff(part * 0.70710678118654752f)) * (WGT); \
        oacc[0] += coef * U0.x; oacc[1] += coef * U0.y;                          \
        oacc[2] += coef * U0.z; oacc[3] += coef * U0.w;                          \
        oacc[4] += coef * U1.x; oacc[5] += coef * U1.y;                          \
        oacc[6] += coef * U1.z; oacc[7] += coef * U1.w;                          \
    }

    // prologue: expert 0 -> A set
    float4 dA0, dA1, uA0, uA1, dB0, dB1, uB0, uB1;
    {
        long iA = __shfl(myidx, 0);
        const float* drA = &w_down[iA * 512 + ln * 8];
        const float* urA = &w_up  [iA * 512 + ln * 8];
        dA0 = *(const float4*)&drA[0]; dA1 = *(const float4*)&drA[4];
        uA0 = *(const float4*)&urA[0]; uA1 = *(const float4*)&urA[4];
    }
    for (int e = 0; e < 32; e += 2) {
        // issue expert e+1 -> B set (lands under A's compute)
        {
            long iB = __shfl(myidx, e + 1);
            const float* drB = &w_down[iB * 512 + ln * 8];
            const float* urB = &w_up  [iB * 512 + ln * 8];
            dB0 = *(const float4*)&drB[0]; dB1 = *(const float4*)&drB[4];
            uB0 = *(const float4*)&urB[0]; uB1 = *(const float4*)&urB[4];
        }
        // compute expert e from A
        {
            float wgtA = __shfl(mywgt, e);
            EXPERT_COMPUTE(dA0, dA1, uA0, uA1, wgtA);
        }
        // issue expert e+2 -> A set (lands under B's compute)
        if (e + 2 < 32) {
            long iA = __shfl(myidx, e + 2);
            const float* drA = &w_down[iA * 512 + ln * 8];
            const float* urA = &w_up  [iA * 512 + ln * 8];
            dA0 = *(const float4*)&drA[0]; dA1 = *(const float4*)&drA[4];
            uA0 = *(const float4*)&urA[0]; uA1 = *(const float4*)&urA[4];
        }
        // compute expert e+1 from B
        {
            float wgtB = __shfl(mywgt, e + 1);
            EXPERT_COMPUTE(dB0, dB1, uB0, uB1, wgtB);
        }
    }
#undef EXPERT_COMPUTE

#pragma unroll
    for (int j = 0; j < 8; ++j) wacc[wv][ln * 8 + j] = oacc[j];
    __syncthreads();

    float* orow = &out[(c * 1024 + n) * 512];
    for (int d = t; d < 512; d += 256)
        orow[d] = wacc[0][d] + wacc[1][d] + wacc[2][d] + wacc[3][d];
}

extern "C" void kernel_launch(void* const* d_in, const int* in_sizes, int n_in,
                              void* d_out, int out_size, void* d_ws, size_t ws_size,
                              hipStream_t stream) {
    const float* x      = (const float*)d_in[0];
    const float* Wq     = (const float*)d_in[1];
    const float* keys   = (const float*)d_in[2];
    const float* w_down = (const float*)d_in[3];
    const float* w_up   = (const float*)d_in[4];
    float* out = (float*)d_out;

    char* ws = (char*)d_ws;
    float* q     = (float*)ws;                               // 32 MiB
    int*   widx  = (int*)(ws + 2048UL * 4096 * 4);           // 1 MiB
    float* wcoef = (float*)(ws + 2048UL * 4096 * 4 + 262144UL * 4);
    float* KT    = (float*)(ws + 2048UL * 4096 * 4 + 2 * 262144UL * 4);  // 4 MiB

    k0_transpose<<<256, 256, 0, stream>>>(keys, KT);
    k1_gemm<<<dim3(32, 16), 256, 0, stream>>>(x, Wq, q);
    k2_scores<<<1024, 256, 0, stream>>>(q, KT, widx, wcoef);
    k3_experts<<<2048, 256, 0, stream>>>(x, w_down, w_up, widx, wcoef, out);
}